// Round 11
// baseline (285.410 us; speedup 1.0000x reference)
//
#include <hip/hip_runtime.h>
#include <hip/hip_bf16.h>

#define NN   10000
#define BB   4
#define DD   128
#define HIDD 256
#define NEG  0.2f

using bf16 = __hip_bfloat16;
typedef __bf16 bf16x8 __attribute__((ext_vector_type(8)));
typedef float  f32x4  __attribute__((ext_vector_type(4)));

__device__ __forceinline__ float lrelu(float x) { return x > 0.f ? x : NEG * x; }

__device__ __forceinline__ unsigned pack2(float a, float b) {
    unsigned lo = __bfloat16_as_ushort(__float2bfloat16(a));
    unsigned hi = __bfloat16_as_ushort(__float2bfloat16(b));
    return lo | (hi << 16);
}

// ---------------- fp32 -> bf16 feature conversion ----------------
__global__ void convert_kernel(const float* __restrict__ x, bf16* __restrict__ y, int n) {
    int i = blockIdx.x * 256 + threadIdx.x;
    if (i < n) y[i] = __float2bfloat16(x[i]);
}

// ---------------- fused prep: zero counts + transpose/convert W1, W2 ----------------
__global__ void prep_kernel(int* counts,
                            const float* __restrict__ W1, bf16* __restrict__ Wt1,
                            const float* __restrict__ W2, bf16* __restrict__ Wt2) {
    int idx = blockIdx.x * 256 + threadIdx.x;
    if (idx < NN) { counts[idx] = 0; return; }
    idx -= NN;
    if (idx < DD * HIDD) {
        int k = idx / HIDD, n = idx % HIDD;
        Wt1[(size_t)n * DD + k] = __float2bfloat16(W1[idx]);
        return;
    }
    idx -= DD * HIDD;
    if (idx < HIDD * HIDD) {
        int k = idx / HIDD, n = idx % HIDD;
        Wt2[(size_t)n * HIDD + k] = __float2bfloat16(W2[idx]);
    }
}

// ---------------- CSR build ----------------
__global__ void hist_kernel(const int* __restrict__ dstv, int* counts, int E) {
    int e = blockIdx.x * 256 + threadIdx.x;
    if (e < E) atomicAdd(&counts[dstv[e]], 1);
}

__global__ __launch_bounds__(1024) void scan_kernel(const int* __restrict__ counts,
                                                    int* row_start, int* cursor) {
    __shared__ int part[1024];
    int t = threadIdx.x;
    const int CH = (NN + 1023) / 1024;  // 10
    int base = t * CH;
    int s = 0;
    for (int j = 0; j < CH; j++) { int idx = base + j; if (idx < NN) s += counts[idx]; }
    part[t] = s;
    __syncthreads();
    for (int off = 1; off < 1024; off <<= 1) {
        int v = (t >= off) ? part[t - off] : 0;
        __syncthreads();
        part[t] += v;
        __syncthreads();
    }
    int excl = (t == 0) ? 0 : part[t - 1];
    for (int j = 0; j < CH; j++) {
        int idx = base + j;
        if (idx < NN) { row_start[idx] = excl; cursor[idx] = excl; excl += counts[idx]; }
    }
    if (t == 1023) row_start[NN] = part[1023];
}

__global__ void scatter_kernel(const int* __restrict__ srcv, const int* __restrict__ dstv,
                               int* cursor, int* csr_src, int E) {
    int e = blockIdx.x * 256 + threadIdx.x;
    if (e < E) {
        int d = dstv[e];
        int p = atomicAdd(&cursor[d], 1);
        csr_src[p] = srcv[e];
    }
}

// ---------------- persistent-B GEMM, 8-wave blocks ----------------
// Grid: 4g (XCD affinity, fastest) x 2head x 40 tiles = 320 blocks x 512 thr.
// Block: 256 rows x 128 cols (one head). B panel staged to LDS once (wave w
// stages fi=w), then barrier-free MFMA loop; per wave 32 rows.
// Swapped-operand MFMA: mfma(bv, av) -> lane holds 4 consecutive OUTPUT CHANNELS
// (ch = head*128 + fi*16 + lq*4 + r) of ONE node row (nd = m0 + rb*16 + lm).
template <int K>
__global__ __launch_bounds__(512) void gemm_kernel(const bf16* __restrict__ A,
                                                   const bf16* __restrict__ Wt,
                                                   const float* __restrict__ a_src,
                                                   const float* __restrict__ a_dst,
                                                   bf16* __restrict__ H,
                                                   float* __restrict__ als,
                                                   float* __restrict__ ald) {
    constexpr int NF = K / 32;                 // k-chunks of 32
    __shared__ bf16 Bs[8 * NF * 512];          // 32 KB (K=128) / 64 KB (K=256)

    int b     = blockIdx.x;
    int g     = b & 3;
    int r     = b >> 2;
    int head  = r & 1;
    int tile  = r >> 1;                        // 0..39 (256 rows each)
    int wave  = threadIdx.x >> 6, lane = threadIdx.x & 63;
    int lm    = lane & 15, lq = lane >> 4;

    const bf16* Wh = Wt + (size_t)head * 128 * K;

    // stage B panel: wave w stages fragment row fi = w (NF chunks of 1 KB)
#pragma unroll
    for (int ks = 0; ks < NF; ks++) {
        const bf16* src = Wh + (size_t)(wave * 16 + lm) * K + ks * 32 + lq * 8;
        __builtin_amdgcn_global_load_lds(
            (const __attribute__((address_space(1))) void*)src,
            (__attribute__((address_space(3))) void*)(Bs + (wave * NF + ks) * 512),
            16, 0, 0);
    }
    __syncthreads();

    // hoist attention vectors for this lane's channel quads
    float4 asv[8], adv[8];
#pragma unroll
    for (int fi = 0; fi < 8; fi++) {
        asv[fi] = *(const float4*)(a_src + head * 128 + fi * 16 + lq * 4);
        adv[fi] = *(const float4*)(a_dst + head * 128 + fi * 16 + lq * 4);
    }

    int m0 = tile * 256 + wave * 32;
    int rA = min(m0 + lm, NN - 1);
    int rB = min(m0 + 16 + lm, NN - 1);
    const bf16* Ar0 = A + ((size_t)g * NN + rA) * K + lq * 8;
    const bf16* Ar1 = A + ((size_t)g * NN + rB) * K + lq * 8;

    f32x4 acc[2][8];
#pragma unroll
    for (int rb = 0; rb < 2; rb++)
#pragma unroll
        for (int i = 0; i < 8; i++) acc[rb][i] = (f32x4){0.f, 0.f, 0.f, 0.f};

#pragma unroll
    for (int ks = 0; ks < NF; ks++) {
        bf16x8 a0 = *(const bf16x8*)(Ar0 + ks * 32);
        bf16x8 a1 = *(const bf16x8*)(Ar1 + ks * 32);
#pragma unroll
        for (int fi = 0; fi < 8; fi++) {
            bf16x8 bv = *(const bf16x8*)(Bs + ((size_t)(fi * NF + ks) * 64 + lane) * 8);
            acc[0][fi] = __builtin_amdgcn_mfma_f32_16x16x32_bf16(bv, a0, acc[0][fi], 0, 0, 0);
            acc[1][fi] = __builtin_amdgcn_mfma_f32_16x16x32_bf16(bv, a1, acc[1][fi], 0, 0, 0);
        }
    }

#pragma unroll
    for (int rb = 0; rb < 2; rb++) {
        int nd = m0 + rb * 16 + lm;
        float ps = 0.f, pd = 0.f;
        bool ok = nd < NN;
        size_t hb = ((size_t)g * NN + (ok ? nd : 0)) * HIDD + head * 128 + lq * 4;
#pragma unroll
        for (int fi = 0; fi < 8; fi++) {
            f32x4 v = acc[rb][fi];
            ps += v[0] * asv[fi].x + v[1] * asv[fi].y + v[2] * asv[fi].z + v[3] * asv[fi].w;
            pd += v[0] * adv[fi].x + v[1] * adv[fi].y + v[2] * adv[fi].z + v[3] * adv[fi].w;
            if (ok) {
                uint2 pk = {pack2(v[0], v[1]), pack2(v[2], v[3])};
                *(uint2*)(H + hb + fi * 16) = pk;
            }
        }
        // reduce channel partial sums across the 4 lq lanes of this node
        ps += __shfl_xor(ps, 16); ps += __shfl_xor(ps, 32);
        pd += __shfl_xor(pd, 16); pd += __shfl_xor(pd, 32);
        if (lq == 0 && ok) {
            als[((size_t)g * NN + nd) * 2 + head] = ps;
            ald[((size_t)g * NN + nd) * 2 + head] = pd;
        }
    }
}

// ---------------- SINGLE-PASS softmax-aggregate + bias + LN + ReLU, one WAVE per (g,n) ----------------
template <typename OT>
__global__ __launch_bounds__(256) void node_kernel(const int* __restrict__ row_start,
                                                   const int* __restrict__ csr_src,
                                                   const float2* __restrict__ als2,
                                                   const float2* __restrict__ ald2,
                                                   const bf16* __restrict__ H,
                                                   const float* __restrict__ bias,
                                                   const float* __restrict__ gam,
                                                   const float* __restrict__ bet,
                                                   OT* __restrict__ out) {
    int b = blockIdx.x;
    int g = b & 3;
    int wave = threadIdx.x >> 6, lane = threadIdx.x & 63;
    int n = (b >> 2) * 4 + wave;
    if (n >= NN) return;
    int start = row_start[n];
    int deg   = row_start[n + 1] - start;

    int grp = lane >> 5, lch = lane & 31;
    int hd_g = lch >> 4;
    const float* alsf = (const float*)(als2 + (size_t)g * NN);  // [node*2 + head]
    float2 ad = ald2[(size_t)g * NN + n];
    float adh = hd_g ? ad.y : ad.x;
    const int* Sr = csr_src + start;
    const bf16* Hg = H + (size_t)g * NN * HIDD;

    float acc[8] = {0.f, 0.f, 0.f, 0.f, 0.f, 0.f, 0.f, 0.f};
    float dsum = 0.f;

#define EDGE_FMA(ss, qq)                                                \
    {                                                                   \
        float wv = __expf(lrelu(alsf[(size_t)(ss) * 2 + hd_g] + adh));  \
        dsum += wv;                                                     \
        acc[0] = fmaf(wv, __uint_as_float(qq.x << 16), acc[0]);         \
        acc[1] = fmaf(wv, __uint_as_float(qq.x & 0xffff0000u), acc[1]); \
        acc[2] = fmaf(wv, __uint_as_float(qq.y << 16), acc[2]);         \
        acc[3] = fmaf(wv, __uint_as_float(qq.y & 0xffff0000u), acc[3]); \
        acc[4] = fmaf(wv, __uint_as_float(qq.z << 16), acc[4]);         \
        acc[5] = fmaf(wv, __uint_as_float(qq.z & 0xffff0000u), acc[5]); \
        acc[6] = fmaf(wv, __uint_as_float(qq.w << 16), acc[6]);         \
        acc[7] = fmaf(wv, __uint_as_float(qq.w & 0xffff0000u), acc[7]); \
    }

    int i = grp;
    // 8 edges per group in flight (16 per wave-iteration)
    for (; i + 14 < deg; i += 16) {
        int s0 = Sr[i],      s1 = Sr[i + 2],  s2 = Sr[i + 4],  s3 = Sr[i + 6];
        int s4 = Sr[i + 8],  s5 = Sr[i + 10], s6 = Sr[i + 12], s7 = Sr[i + 14];
        uint4 q0 = *(const uint4*)(Hg + (size_t)s0 * HIDD + lch * 8);
        uint4 q1 = *(const uint4*)(Hg + (size_t)s1 * HIDD + lch * 8);
        uint4 q2 = *(const uint4*)(Hg + (size_t)s2 * HIDD + lch * 8);
        uint4 q3 = *(const uint4*)(Hg + (size_t)s3 * HIDD + lch * 8);
        uint4 q4 = *(const uint4*)(Hg + (size_t)s4 * HIDD + lch * 8);
        uint4 q5 = *(const uint4*)(Hg + (size_t)s5 * HIDD + lch * 8);
        uint4 q6 = *(const uint4*)(Hg + (size_t)s6 * HIDD + lch * 8);
        uint4 q7 = *(const uint4*)(Hg + (size_t)s7 * HIDD + lch * 8);
        EDGE_FMA(s0, q0)
        EDGE_FMA(s1, q1)
        EDGE_FMA(s2, q2)
        EDGE_FMA(s3, q3)
        EDGE_FMA(s4, q4)
        EDGE_FMA(s5, q5)
        EDGE_FMA(s6, q6)
        EDGE_FMA(s7, q7)
    }
    for (; i + 6 < deg; i += 8) {
        int s0 = Sr[i], s1 = Sr[i + 2], s2 = Sr[i + 4], s3 = Sr[i + 6];
        uint4 q0 = *(const uint4*)(Hg + (size_t)s0 * HIDD + lch * 8);
        uint4 q1 = *(const uint4*)(Hg + (size_t)s1 * HIDD + lch * 8);
        uint4 q2 = *(const uint4*)(Hg + (size_t)s2 * HIDD + lch * 8);
        uint4 q3 = *(const uint4*)(Hg + (size_t)s3 * HIDD + lch * 8);
        EDGE_FMA(s0, q0)
        EDGE_FMA(s1, q1)
        EDGE_FMA(s2, q2)
        EDGE_FMA(s3, q3)
    }
    for (; i < deg; i += 2) {
        int s0 = Sr[i];
        uint4 q0 = *(const uint4*)(Hg + (size_t)s0 * HIDD + lch * 8);
        EDGE_FMA(s0, q0)
    }
#undef EDGE_FMA

    // fold group1 into group0 (lch identical across groups -> same head)
#pragma unroll
    for (int j = 0; j < 8; j++) acc[j] += __shfl_xor(acc[j], 32);
    dsum += __shfl_xor(dsum, 32);
    float rdh = 1.f / dsum;

    // normalize + bias + LN over 256 channels
    float4 bi0 = *(const float4*)(bias + lch * 8);
    float4 bi1 = *(const float4*)(bias + lch * 8 + 4);
    float v[8];
    v[0] = fmaf(acc[0], rdh, bi0.x); v[1] = fmaf(acc[1], rdh, bi0.y);
    v[2] = fmaf(acc[2], rdh, bi0.z); v[3] = fmaf(acc[3], rdh, bi0.w);
    v[4] = fmaf(acc[4], rdh, bi1.x); v[5] = fmaf(acc[5], rdh, bi1.y);
    v[6] = fmaf(acc[6], rdh, bi1.z); v[7] = fmaf(acc[7], rdh, bi1.w);

    float s1 = 0.f, s2 = 0.f;
#pragma unroll
    for (int j = 0; j < 8; j++) { s1 += v[j]; s2 += v[j] * v[j]; }
#pragma unroll
    for (int off = 16; off; off >>= 1) {
        s1 += __shfl_xor(s1, off);
        s2 += __shfl_xor(s2, off);
    }
    float mu  = s1 * (1.f / HIDD);
    float var = s2 * (1.f / HIDD) - mu * mu;
    float rs  = rsqrtf(var + 1e-5f);

    float4 ga0 = *(const float4*)(gam + lch * 8);
    float4 ga1 = *(const float4*)(gam + lch * 8 + 4);
    float4 be0 = *(const float4*)(bet + lch * 8);
    float4 be1 = *(const float4*)(bet + lch * 8 + 4);
    float gaf[8] = {ga0.x, ga0.y, ga0.z, ga0.w, ga1.x, ga1.y, ga1.z, ga1.w};
    float bef[8] = {be0.x, be0.y, be0.z, be0.w, be1.x, be1.y, be1.z, be1.w};

    float o[8];
#pragma unroll
    for (int j = 0; j < 8; j++)
        o[j] = fmaxf((v[j] - mu) * rs * gaf[j] + bef[j], 0.f);

    if (grp == 0) {
        size_t base = ((size_t)g * NN + n) * HIDD + lch * 8;
        if constexpr (sizeof(OT) == 2) {
            uint4 pk;
            pk.x = pack2(o[0], o[1]); pk.y = pack2(o[2], o[3]);
            pk.z = pack2(o[4], o[5]); pk.w = pack2(o[6], o[7]);
            *(uint4*)((bf16*)out + base) = pk;
        } else {
            *(float4*)((float*)out + base)     = make_float4(o[0], o[1], o[2], o[3]);
            *(float4*)((float*)out + base + 4) = make_float4(o[4], o[5], o[6], o[7]);
        }
    }
}

// ---------------- launch ----------------
extern "C" void kernel_launch(void* const* d_in, const int* in_sizes, int n_in,
                              void* d_out, int out_size, void* d_ws, size_t ws_size,
                              hipStream_t stream) {
    const float* feature = (const float*)d_in[0];
    const int*   ei      = (const int*)d_in[1];
    const float* W1      = (const float*)d_in[2];
    const float* a_src1  = (const float*)d_in[3];
    const float* a_dst1  = (const float*)d_in[4];
    const float* b1      = (const float*)d_in[5];
    const float* g1      = (const float*)d_in[6];
    const float* be1     = (const float*)d_in[7];
    const float* W2      = (const float*)d_in[8];
    const float* a_src2  = (const float*)d_in[9];
    const float* a_dst2  = (const float*)d_in[10];
    const float* b2      = (const float*)d_in[11];
    const float* g2      = (const float*)d_in[12];
    const float* be2     = (const float*)d_in[13];
    float* out = (float*)d_out;

    const int E = in_sizes[1] / 2;
    const int* srcv = ei;
    const int* dstv = ei + E;

    char* w = (char*)d_ws;
    auto alloc = [&](size_t bytes) -> char* {
        char* p = w;
        w += (bytes + 255) & ~(size_t)255;
        return p;
    };
    int*    counts    = (int*)alloc(sizeof(int) * NN);
    int*    row_start = (int*)alloc(sizeof(int) * (NN + 1));
    int*    cursor    = (int*)alloc(sizeof(int) * NN);
    int*    csr_src   = (int*)alloc(sizeof(int) * E);
    float*  als       = (float*)alloc(sizeof(float) * (size_t)BB * NN * 2);
    float*  ald       = (float*)alloc(sizeof(float) * (size_t)BB * NN * 2);
    bf16*   featbf    = (bf16*)alloc(sizeof(bf16) * (size_t)BB * NN * DD);
    bf16*   h         = (bf16*)alloc(sizeof(bf16) * (size_t)BB * NN * HIDD);
    bf16*   x2        = (bf16*)alloc(sizeof(bf16) * (size_t)BB * NN * HIDD);
    bf16*   Wt1       = (bf16*)alloc(sizeof(bf16) * DD * HIDD);
    bf16*   Wt2       = (bf16*)alloc(sizeof(bf16) * HIDD * HIDD);

    int nblk = ((NN + 3) / 4) * 4;
    int gblk = 4 * 2 * ((NN + 255) / 256);  // g fastest (XCD affinity), head, tile

    // prep (zero counts + convwt W1/W2) + feature convert + CSR build
    {
        int ptot = NN + DD * HIDD + HIDD * HIDD;
        prep_kernel<<<(ptot + 255) / 256, 256, 0, stream>>>(counts, W1, Wt1, W2, Wt2);
        int nf = BB * NN * DD;
        convert_kernel<<<(nf + 255) / 256, 256, 0, stream>>>(feature, featbf, nf);
    }
    hist_kernel<<<(E + 255) / 256, 256, 0, stream>>>(dstv, counts, E);
    scan_kernel<<<1, 1024, 0, stream>>>(counts, row_start, cursor);
    scatter_kernel<<<(E + 255) / 256, 256, 0, stream>>>(srcv, dstv, cursor, csr_src, E);

    // Layer 1
    gemm_kernel<DD><<<gblk, 512, 0, stream>>>(featbf, Wt1, a_src1, a_dst1, h, als, ald);
    node_kernel<bf16><<<nblk, 256, 0, stream>>>(row_start, csr_src, (const float2*)als, (const float2*)ald,
                                                h, b1, g1, be1, x2);

    // Layer 2
    gemm_kernel<HIDD><<<gblk, 512, 0, stream>>>(x2, Wt2, a_src2, a_dst2, h, als, ald);
    node_kernel<float><<<nblk, 256, 0, stream>>>(row_start, csr_src, (const float2*)als, (const float2*)ald,
                                                 h, b2, g2, be2, out);
}

// Round 12
// 252.132 us; speedup vs baseline: 1.1320x; 1.1320x over previous
//
#include <hip/hip_runtime.h>
#include <hip/hip_bf16.h>

#define NN   10000
#define BB   4
#define DD   128
#define HIDD 256
#define NEG  0.2f

using bf16 = __hip_bfloat16;
typedef __bf16 bf16x8 __attribute__((ext_vector_type(8)));
typedef float  f32x4  __attribute__((ext_vector_type(4)));

__device__ __forceinline__ float lrelu(float x) { return x > 0.f ? x : NEG * x; }

__device__ __forceinline__ unsigned pack2(float a, float b) {
    unsigned lo = __bfloat16_as_ushort(__float2bfloat16(a));
    unsigned hi = __bfloat16_as_ushort(__float2bfloat16(b));
    return lo | (hi << 16);
}

// ---------------- fused prep: feature fp32->bf16 (x4), zero counts, Wt1, Wt2 ----------------
#define NF4 (BB * NN * DD / 4)
__global__ void prep_kernel(const float* __restrict__ feat, bf16* __restrict__ featbf,
                            int* counts,
                            const float* __restrict__ W1, bf16* __restrict__ Wt1,
                            const float* __restrict__ W2, bf16* __restrict__ Wt2) {
    int idx = blockIdx.x * 256 + threadIdx.x;
    if (idx < NF4) {
        float4 v = *(const float4*)(feat + (size_t)idx * 4);
        uint2 pk = {pack2(v.x, v.y), pack2(v.z, v.w)};
        *(uint2*)(featbf + (size_t)idx * 4) = pk;
        return;
    }
    idx -= NF4;
    if (idx < NN) { counts[idx] = 0; return; }
    idx -= NN;
    if (idx < DD * HIDD) {
        int k = idx / HIDD, n = idx % HIDD;
        Wt1[(size_t)n * DD + k] = __float2bfloat16(W1[idx]);
        return;
    }
    idx -= DD * HIDD;
    if (idx < HIDD * HIDD) {
        int k = idx / HIDD, n = idx % HIDD;
        Wt2[(size_t)n * HIDD + k] = __float2bfloat16(W2[idx]);
    }
}

// ---------------- CSR build ----------------
__global__ void hist_kernel(const int* __restrict__ dstv, int* counts, int E) {
    int e = blockIdx.x * 256 + threadIdx.x;
    if (e < E) atomicAdd(&counts[dstv[e]], 1);
}

__global__ __launch_bounds__(1024) void scan_kernel(const int* __restrict__ counts,
                                                    int* row_start, int* cursor) {
    __shared__ int part[1024];
    int t = threadIdx.x;
    const int CH = (NN + 1023) / 1024;  // 10
    int base = t * CH;
    int s = 0;
    for (int j = 0; j < CH; j++) { int idx = base + j; if (idx < NN) s += counts[idx]; }
    part[t] = s;
    __syncthreads();
    for (int off = 1; off < 1024; off <<= 1) {
        int v = (t >= off) ? part[t - off] : 0;
        __syncthreads();
        part[t] += v;
        __syncthreads();
    }
    int excl = (t == 0) ? 0 : part[t - 1];
    for (int j = 0; j < CH; j++) {
        int idx = base + j;
        if (idx < NN) { row_start[idx] = excl; cursor[idx] = excl; excl += counts[idx]; }
    }
    if (t == 1023) row_start[NN] = part[1023];
}

__global__ void scatter_kernel(const int* __restrict__ srcv, const int* __restrict__ dstv,
                               int* cursor, int* csr_src, int E) {
    int e = blockIdx.x * 256 + threadIdx.x;
    if (e < E) {
        int d = dstv[e];
        int p = atomicAdd(&cursor[d], 1);
        csr_src[p] = srcv[e];
    }
}

// ---------------- GEMM + fused attention coefficients ----------------
// R9's proven chunked structure (128 rows x 128 cols per 256-thr block, barriered
// 128-wide K-chunks staged to LDS via global_load_lds in fragment order) with the
// swapped-operand epilogue: mfma(bv, av) -> lane holds 4 consecutive OUTPUT
// CHANNELS (ch = head*128 + fi*16 + lq*4 + r) of ONE node row (nd = m0+rb*16+lm).
// Epilogue: 16 packed 8B H-stores/lane; als/ald reduce over lq via 2 shfl_xor.
template <int K>
__global__ __launch_bounds__(256) void gemm_kernel(const bf16* __restrict__ A,
                                                   const bf16* __restrict__ Wt,
                                                   const float* __restrict__ a_src,
                                                   const float* __restrict__ a_dst,
                                                   bf16* __restrict__ H,
                                                   float* __restrict__ als,
                                                   float* __restrict__ ald) {
    __shared__ bf16 Bs[128 * 128];  // 32 KB

    int b    = blockIdx.x;
    int g    = b & 3;
    int r    = b >> 2;
    int head = r & 1;
    int wave = threadIdx.x >> 6;
    int m0   = (r >> 1) * 128 + wave * 32;
    int lane = threadIdx.x & 63;
    int lm   = lane & 15, lq = lane >> 4;

    int rowA = min(m0 + lm, NN - 1);
    int rowB = min(m0 + 16 + lm, NN - 1);
    const bf16* Ar0 = A + ((size_t)g * NN + rowA) * K + lq * 8;
    const bf16* Ar1 = A + ((size_t)g * NN + rowB) * K + lq * 8;
    const bf16* Wh  = Wt + (size_t)head * 128 * K;

    f32x4 acc[2][8];
#pragma unroll
    for (int rb = 0; rb < 2; rb++)
#pragma unroll
        for (int i = 0; i < 8; i++) acc[rb][i] = (f32x4){0.f, 0.f, 0.f, 0.f};

    for (int kb = 0; kb < K; kb += 128) {
        if (kb) __syncthreads();  // protect previous chunk's reads
        // stage this K-chunk: wave w fills segments j = w*8 .. w*8+7 (1 KB each)
#pragma unroll
        for (int jj = 0; jj < 8; jj++) {
            int j  = wave * 8 + jj;
            int fi = j >> 2, ks = j & 3;
            const bf16* src = Wh + (size_t)(fi * 16 + lm) * K + kb + ks * 32 + lq * 8;
            __builtin_amdgcn_global_load_lds(
                (const __attribute__((address_space(1))) void*)src,
                (__attribute__((address_space(3))) void*)(Bs + j * 512),
                16, 0, 0);
        }
        __syncthreads();

        // prefetch all A fragments for this chunk (8 x b128)
        bf16x8 a0[4], a1[4];
#pragma unroll
        for (int ks = 0; ks < 4; ks++) {
            a0[ks] = *(const bf16x8*)(Ar0 + kb + ks * 32);
            a1[ks] = *(const bf16x8*)(Ar1 + kb + ks * 32);
        }
        // pure LDS-read + MFMA inner loop (swapped operands)
#pragma unroll
        for (int ks = 0; ks < 4; ks++) {
#pragma unroll
            for (int fi = 0; fi < 8; fi++) {
                bf16x8 bv = *(const bf16x8*)(Bs + ((fi * 4 + ks) * 64 + lane) * 8);
                acc[0][fi] = __builtin_amdgcn_mfma_f32_16x16x32_bf16(bv, a0[ks], acc[0][fi], 0, 0, 0);
                acc[1][fi] = __builtin_amdgcn_mfma_f32_16x16x32_bf16(bv, a1[ks], acc[1][fi], 0, 0, 0);
            }
        }
    }

    // hoist attention vectors for this lane's channel quads
    float4 asv[8], adv[8];
#pragma unroll
    for (int fi = 0; fi < 8; fi++) {
        asv[fi] = *(const float4*)(a_src + head * 128 + fi * 16 + lq * 4);
        adv[fi] = *(const float4*)(a_dst + head * 128 + fi * 16 + lq * 4);
    }

#pragma unroll
    for (int rb = 0; rb < 2; rb++) {
        int nd = m0 + rb * 16 + lm;
        float ps = 0.f, pd = 0.f;
        bool ok = nd < NN;
        size_t hb = ((size_t)g * NN + (ok ? nd : 0)) * HIDD + head * 128 + lq * 4;
#pragma unroll
        for (int fi = 0; fi < 8; fi++) {
            f32x4 v = acc[rb][fi];
            ps += v[0] * asv[fi].x + v[1] * asv[fi].y + v[2] * asv[fi].z + v[3] * asv[fi].w;
            pd += v[0] * adv[fi].x + v[1] * adv[fi].y + v[2] * adv[fi].z + v[3] * adv[fi].w;
            if (ok) {
                uint2 pk = {pack2(v[0], v[1]), pack2(v[2], v[3])};
                *(uint2*)(H + hb + fi * 16) = pk;
            }
        }
        // reduce channel partial sums across the 4 lq lanes of this node
        ps += __shfl_xor(ps, 16); ps += __shfl_xor(ps, 32);
        pd += __shfl_xor(pd, 16); pd += __shfl_xor(pd, 32);
        if (lq == 0 && ok) {
            als[((size_t)g * NN + nd) * 2 + head] = ps;
            ald[((size_t)g * NN + nd) * 2 + head] = pd;
        }
    }
}

// ---------------- SINGLE-PASS softmax-aggregate + bias + LN + ReLU, one WAVE per (g,n) ----------------
// (exact R9 version: 4-deep unroll, VGPR 32, occupancy ~61%)
template <typename OT>
__global__ __launch_bounds__(256) void node_kernel(const int* __restrict__ row_start,
                                                   const int* __restrict__ csr_src,
                                                   const float2* __restrict__ als2,
                                                   const float2* __restrict__ ald2,
                                                   const bf16* __restrict__ H,
                                                   const float* __restrict__ bias,
                                                   const float* __restrict__ gam,
                                                   const float* __restrict__ bet,
                                                   OT* __restrict__ out) {
    int b = blockIdx.x;
    int g = b & 3;
    int wave = threadIdx.x >> 6, lane = threadIdx.x & 63;
    int n = (b >> 2) * 4 + wave;
    if (n >= NN) return;
    int start = row_start[n];
    int deg   = row_start[n + 1] - start;

    int grp = lane >> 5, lch = lane & 31;
    int hd_g = lch >> 4;
    const float* alsf = (const float*)(als2 + (size_t)g * NN);  // [node*2 + head]
    float2 ad = ald2[(size_t)g * NN + n];
    float adh = hd_g ? ad.y : ad.x;
    const int* Sr = csr_src + start;
    const bf16* Hg = H + (size_t)g * NN * HIDD;

    float acc[8] = {0.f, 0.f, 0.f, 0.f, 0.f, 0.f, 0.f, 0.f};
    float dsum = 0.f;

#define EDGE_FMA(ss, qq)                                                \
    {                                                                   \
        float wv = __expf(lrelu(alsf[(size_t)(ss) * 2 + hd_g] + adh));  \
        dsum += wv;                                                     \
        acc[0] = fmaf(wv, __uint_as_float(qq.x << 16), acc[0]);         \
        acc[1] = fmaf(wv, __uint_as_float(qq.x & 0xffff0000u), acc[1]); \
        acc[2] = fmaf(wv, __uint_as_float(qq.y << 16), acc[2]);         \
        acc[3] = fmaf(wv, __uint_as_float(qq.y & 0xffff0000u), acc[3]); \
        acc[4] = fmaf(wv, __uint_as_float(qq.z << 16), acc[4]);         \
        acc[5] = fmaf(wv, __uint_as_float(qq.z & 0xffff0000u), acc[5]); \
        acc[6] = fmaf(wv, __uint_as_float(qq.w << 16), acc[6]);         \
        acc[7] = fmaf(wv, __uint_as_float(qq.w & 0xffff0000u), acc[7]); \
    }

    int i = grp;
    for (; i + 6 < deg; i += 8) {
        int s0 = Sr[i], s1 = Sr[i + 2], s2 = Sr[i + 4], s3 = Sr[i + 6];
        uint4 q0 = *(const uint4*)(Hg + (size_t)s0 * HIDD + lch * 8);
        uint4 q1 = *(const uint4*)(Hg + (size_t)s1 * HIDD + lch * 8);
        uint4 q2 = *(const uint4*)(Hg + (size_t)s2 * HIDD + lch * 8);
        uint4 q3 = *(const uint4*)(Hg + (size_t)s3 * HIDD + lch * 8);
        EDGE_FMA(s0, q0)
        EDGE_FMA(s1, q1)
        EDGE_FMA(s2, q2)
        EDGE_FMA(s3, q3)
    }
    for (; i < deg; i += 2) {
        int s0 = Sr[i];
        uint4 q0 = *(const uint4*)(Hg + (size_t)s0 * HIDD + lch * 8);
        EDGE_FMA(s0, q0)
    }
#undef EDGE_FMA

    // fold group1 into group0 (lch identical across groups -> same head)
#pragma unroll
    for (int j = 0; j < 8; j++) acc[j] += __shfl_xor(acc[j], 32);
    dsum += __shfl_xor(dsum, 32);
    float rdh = 1.f / dsum;

    // normalize + bias + LN over 256 channels
    float4 bi0 = *(const float4*)(bias + lch * 8);
    float4 bi1 = *(const float4*)(bias + lch * 8 + 4);
    float v[8];
    v[0] = fmaf(acc[0], rdh, bi0.x); v[1] = fmaf(acc[1], rdh, bi0.y);
    v[2] = fmaf(acc[2], rdh, bi0.z); v[3] = fmaf(acc[3], rdh, bi0.w);
    v[4] = fmaf(acc[4], rdh, bi1.x); v[5] = fmaf(acc[5], rdh, bi1.y);
    v[6] = fmaf(acc[6], rdh, bi1.z); v[7] = fmaf(acc[7], rdh, bi1.w);

    float s1 = 0.f, s2 = 0.f;
#pragma unroll
    for (int j = 0; j < 8; j++) { s1 += v[j]; s2 += v[j] * v[j]; }
#pragma unroll
    for (int off = 16; off; off >>= 1) {
        s1 += __shfl_xor(s1, off);
        s2 += __shfl_xor(s2, off);
    }
    float mu  = s1 * (1.f / HIDD);
    float var = s2 * (1.f / HIDD) - mu * mu;
    float rs  = rsqrtf(var + 1e-5f);

    float4 ga0 = *(const float4*)(gam + lch * 8);
    float4 ga1 = *(const float4*)(gam + lch * 8 + 4);
    float4 be0 = *(const float4*)(bet + lch * 8);
    float4 be1 = *(const float4*)(bet + lch * 8 + 4);
    float gaf[8] = {ga0.x, ga0.y, ga0.z, ga0.w, ga1.x, ga1.y, ga1.z, ga1.w};
    float bef[8] = {be0.x, be0.y, be0.z, be0.w, be1.x, be1.y, be1.z, be1.w};

    float o[8];
#pragma unroll
    for (int j = 0; j < 8; j++)
        o[j] = fmaxf((v[j] - mu) * rs * gaf[j] + bef[j], 0.f);

    if (grp == 0) {
        size_t base = ((size_t)g * NN + n) * HIDD + lch * 8;
        if constexpr (sizeof(OT) == 2) {
            uint4 pk;
            pk.x = pack2(o[0], o[1]); pk.y = pack2(o[2], o[3]);
            pk.z = pack2(o[4], o[5]); pk.w = pack2(o[6], o[7]);
            *(uint4*)((bf16*)out + base) = pk;
        } else {
            *(float4*)((float*)out + base)     = make_float4(o[0], o[1], o[2], o[3]);
            *(float4*)((float*)out + base + 4) = make_float4(o[4], o[5], o[6], o[7]);
        }
    }
}

// ---------------- launch ----------------
extern "C" void kernel_launch(void* const* d_in, const int* in_sizes, int n_in,
                              void* d_out, int out_size, void* d_ws, size_t ws_size,
                              hipStream_t stream) {
    const float* feature = (const float*)d_in[0];
    const int*   ei      = (const int*)d_in[1];
    const float* W1      = (const float*)d_in[2];
    const float* a_src1  = (const float*)d_in[3];
    const float* a_dst1  = (const float*)d_in[4];
    const float* b1      = (const float*)d_in[5];
    const float* g1      = (const float*)d_in[6];
    const float* be1     = (const float*)d_in[7];
    const float* W2      = (const float*)d_in[8];
    const float* a_src2  = (const float*)d_in[9];
    const float* a_dst2  = (const float*)d_in[10];
    const float* b2      = (const float*)d_in[11];
    const float* g2      = (const float*)d_in[12];
    const float* be2     = (const float*)d_in[13];
    float* out = (float*)d_out;

    const int E = in_sizes[1] / 2;
    const int* srcv = ei;
    const int* dstv = ei + E;

    char* w = (char*)d_ws;
    auto alloc = [&](size_t bytes) -> char* {
        char* p = w;
        w += (bytes + 255) & ~(size_t)255;
        return p;
    };
    int*    counts    = (int*)alloc(sizeof(int) * NN);
    int*    row_start = (int*)alloc(sizeof(int) * (NN + 1));
    int*    cursor    = (int*)alloc(sizeof(int) * NN);
    int*    csr_src   = (int*)alloc(sizeof(int) * E);
    float*  als       = (float*)alloc(sizeof(float) * (size_t)BB * NN * 2);
    float*  ald       = (float*)alloc(sizeof(float) * (size_t)BB * NN * 2);
    bf16*   featbf    = (bf16*)alloc(sizeof(bf16) * (size_t)BB * NN * DD);
    bf16*   h         = (bf16*)alloc(sizeof(bf16) * (size_t)BB * NN * HIDD);
    bf16*   x2        = (bf16*)alloc(sizeof(bf16) * (size_t)BB * NN * HIDD);
    bf16*   Wt1       = (bf16*)alloc(sizeof(bf16) * DD * HIDD);
    bf16*   Wt2       = (bf16*)alloc(sizeof(bf16) * HIDD * HIDD);

    int nblk = ((NN + 3) / 4) * 4;
    int gblk = 4 * 2 * ((NN + 127) / 128);  // g fastest (XCD affinity), head, tile

    // fused prep (feature convert x4 + zero counts + Wt1/Wt2) + CSR build
    {
        int ptot = NF4 + NN + DD * HIDD + HIDD * HIDD;
        prep_kernel<<<(ptot + 255) / 256, 256, 0, stream>>>(feature, featbf, counts, W1, Wt1, W2, Wt2);
    }
    hist_kernel<<<(E + 255) / 256, 256, 0, stream>>>(dstv, counts, E);
    scan_kernel<<<1, 1024, 0, stream>>>(counts, row_start, cursor);
    scatter_kernel<<<(E + 255) / 256, 256, 0, stream>>>(srcv, dstv, cursor, csr_src, E);

    // Layer 1
    gemm_kernel<DD><<<gblk, 256, 0, stream>>>(featbf, Wt1, a_src1, a_dst1, h, als, ald);
    node_kernel<bf16><<<nblk, 256, 0, stream>>>(row_start, csr_src, (const float2*)als, (const float2*)ald,
                                                h, b1, g1, be1, x2);

    // Layer 2
    gemm_kernel<HIDD><<<gblk, 256, 0, stream>>>(x2, Wt2, a_src2, a_dst2, h, als, ald);
    node_kernel<float><<<nblk, 256, 0, stream>>>(row_start, csr_src, (const float2*)als, (const float2*)ald,
                                                 h, b2, g2, be2, out);
}